// Round 6
// baseline (1549.805 us; speedup 1.0000x reference)
//
#include <hip/hip_runtime.h>
#include <hip/hip_fp16.h>

// RNN h_{t+1} = tanh(x_t*W_ih + b_ih + b_hh + h_t @ W_hh^T), T=1024, B=64, H=512.
//
// Round 6: ONE WG (512 thr, 8 waves) = ONE batch = ONE CU. Zero cross-WG
// communication (rounds 2/4/5 proved cross-CU exchange costs >=2000cy/step or
// isn't coherent). h passes step-to-step through LDS + one __syncthreads.
//  - Thread (w=tid>>6, i=lane&15, c=lane>>4) owns rows j_m=64w+i+16m (m=0..3)
//    over k-window [128c,128c+128): 256 k-uints (half2 pairs) per thread.
//    208 live in VGPRs (52/row); 12 uint4 chunks (48 uints) live in LDS.
//  - LDS tail layout wtail[chunk][tid]: each wave op reads 64 contiguous 16B
//    lanes -> canonical conflict-free ds_read_b128 (round-3 bug #2 fixed).
//  - VGPR budget 208+~35 < 256 (round-3 bug #1: arrays must fit ARCH VGPRs).
//  - h fp16 in LDS, parity double-buffered; reads are 16-lane broadcasts.
//    Reduce over c: shfl_xor(16)+shfl_xor(32). Published row = 64w+lane
//    (contiguous ds_write_b16). ONE barrier per step.

#define BB 64
#define TT 1024
#define HH 512
#define NREG 52     // half2-uints per row in VGPRs
#define NTAIL 3     // uint4 chunks per row in LDS (12 uints = k-rel 104..127)

typedef _Float16 half2_t __attribute__((ext_vector_type(2)));

__device__ __forceinline__ float dot2f(unsigned h, unsigned w, float acc) {
#if __has_builtin(__builtin_amdgcn_fdot2)
    return __builtin_amdgcn_fdot2(__builtin_bit_cast(half2_t, h),
                                  __builtin_bit_cast(half2_t, w), acc, false);
#else
    __half2 hh = __builtin_bit_cast(__half2, h);
    __half2 ww = __builtin_bit_cast(__half2, w);
    acc = fmaf(__low2float(hh), __low2float(ww), acc);
    return fmaf(__high2float(hh), __high2float(ww), acc);
#endif
}

__device__ __forceinline__ float fast_tanh(float z) {
    float e = __expf(2.0f * z);
    return fmaf(-2.0f, __builtin_amdgcn_rcpf(e + 1.0f), 1.0f);
}

__device__ __forceinline__ unsigned pack_h2(float a, float b) {
    return __builtin_bit_cast(unsigned, __floats2half2_rn(a, b));
}

// 4 dot2s of one h-uint4 against one weight-uint4
#define DOT4(u, wv, acc)                                                 \
    acc = dot2f((u).x, (wv).x, acc); acc = dot2f((u).y, (wv).y, acc);    \
    acc = dot2f((u).z, (wv).z, acc); acc = dot2f((u).w, (wv).w, acc);

__launch_bounds__(512, 2)
__global__ void rnn_cu(const float* __restrict__ x,      // [B,T]
                       const float* __restrict__ W_ih,   // [H]
                       const float* __restrict__ W_hh,   // [H,H]
                       const float* __restrict__ b_ih,   // [H]
                       const float* __restrict__ b_hh,   // [H]
                       const float* __restrict__ W_out,  // [H]
                       const float* __restrict__ b_out,  // [1]
                       float* __restrict__ out)          // [64 + B*H]
{
    const int b    = blockIdx.x;
    const int tid  = threadIdx.x;
    const int w    = tid >> 6;
    const int lane = tid & 63;
    const int i    = lane & 15;
    const int c    = lane >> 4;          // k-window 0..3

    __shared__ __align__(16) unsigned short h16[2][HH];     // 2KB, parity dbuf
    __shared__ float xrow[TT];                              // 4KB
    __shared__ __align__(16) uint4 wtail[4 * NTAIL][512];   // 96KB, [chunk][tid]

    // ---- stage x row ----
    for (int s = tid; s < TT; s += 512) xrow[s] = x[b * TT + s];

    // ---- weights: 4 rows x 128k; 52 uints/row -> VGPR, 12 uints/row -> LDS ----
    const int k0 = c * 128;
    unsigned wr[4][NREG];
#pragma unroll
    for (int m = 0; m < 4; ++m) {
        const int j = 64 * w + i + 16 * m;
        const float4* rp = reinterpret_cast<const float4*>(W_hh + (size_t)j * HH + k0);
#pragma unroll
        for (int q = 0; q < NREG / 2; ++q) {      // 26 float4 -> 52 uints
            const float4 f = rp[q];
            wr[m][2 * q]     = pack_h2(f.x, f.y);
            wr[m][2 * q + 1] = pack_h2(f.z, f.w);
        }
#pragma unroll
        for (int ct = 0; ct < NTAIL; ++ct) {      // 6 float4 -> 3 uint4 chunks
            const float4 f0 = rp[NREG / 2 + 2 * ct];
            const float4 f1 = rp[NREG / 2 + 2 * ct + 1];
            uint4 tv;
            tv.x = pack_h2(f0.x, f0.y); tv.y = pack_h2(f0.z, f0.w);
            tv.z = pack_h2(f1.x, f1.y); tv.w = pack_h2(f1.z, f1.w);
            wtail[m * NTAIL + ct][tid] = tv;
        }
    }

    // published row for this thread: 64w + 16c + i == 64w + lane
    const int jp    = 64 * w + lane;
    const float wih = W_ih[jp];
    const float bias = b_ih[jp] + b_hh[jp];

    __syncthreads();   // xrow + wtail visible

    // ================= main recurrence: 1 barrier / step =================
#pragma unroll 1
    for (int t = 0; t < TT; ++t) {
        const int par = t & 1;
        float v0 = 0.f, v1 = 0.f, v2 = 0.f, v3 = 0.f;
        if (t > 0) {
            const uint4* hb =
                reinterpret_cast<const uint4*>(&h16[par][0]) + c * 16;  // 16 chunks
            float a0 = 0.f, a1 = 0.f, a2 = 0.f, a3 = 0.f;
#pragma unroll
            for (int hc = 0; hc < 13; ++hc) {       // reg-weight part (uints 0..51)
                const uint4 u = hb[hc];
                const uint4 w0 = *reinterpret_cast<const uint4*>(&wr[0][4 * hc]);
                const uint4 w1 = *reinterpret_cast<const uint4*>(&wr[1][4 * hc]);
                const uint4 w2 = *reinterpret_cast<const uint4*>(&wr[2][4 * hc]);
                const uint4 w3 = *reinterpret_cast<const uint4*>(&wr[3][4 * hc]);
                DOT4(u, w0, a0); DOT4(u, w1, a1); DOT4(u, w2, a2); DOT4(u, w3, a3);
            }
#pragma unroll
            for (int ct = 0; ct < NTAIL; ++ct) {    // LDS-tail part (uints 52..63)
                const uint4 u  = hb[13 + ct];
                const uint4 t0 = wtail[0 * NTAIL + ct][tid];
                const uint4 t1 = wtail[1 * NTAIL + ct][tid];
                const uint4 t2 = wtail[2 * NTAIL + ct][tid];
                const uint4 t3 = wtail[3 * NTAIL + ct][tid];
                DOT4(u, t0, a0); DOT4(u, t1, a1); DOT4(u, t2, a2); DOT4(u, t3, a3);
            }
            // combine the 4 k-windows (lanes differing in bits 4,5 share rows)
            a0 += __shfl_xor(a0, 16, 64); a0 += __shfl_xor(a0, 32, 64);
            a1 += __shfl_xor(a1, 16, 64); a1 += __shfl_xor(a1, 32, 64);
            a2 += __shfl_xor(a2, 16, 64); a2 += __shfl_xor(a2, 32, 64);
            a3 += __shfl_xor(a3, 16, 64); a3 += __shfl_xor(a3, 32, 64);
            v0 = a0; v1 = a1; v2 = a2; v3 = a3;
        }
        // this lane publishes row jp = 64w + i + 16c  -> needs v[m = c]
        const float vs01 = (c & 1) ? v1 : v0;
        const float vs23 = (c & 1) ? v3 : v2;
        const float vs   = (c & 2) ? vs23 : vs01;
        const float z = fmaf(xrow[t], wih, vs + bias);
        const float h = fast_tanh(z);
        h16[par ^ 1][jp] = __builtin_bit_cast(unsigned short, (_Float16)h);
        if (t == TT - 1) out[64 + b * HH + jp] = h;
        __syncthreads();
    }

    // ---- epilogue: wave 0 computes out[b] = h_last . W_out + b_out ----
    // last write went to h16[(TT-1+1)&1] = h16[0]
    if (w == 0) {
        const uint4 hv = reinterpret_cast<const uint4*>(&h16[0][0])[lane];
        const float4 w0 = reinterpret_cast<const float4*>(W_out)[2 * lane + 0];
        const float4 w1 = reinterpret_cast<const float4*>(W_out)[2 * lane + 1];
        float s = 0.f;
        __half2 p;
        p = __builtin_bit_cast(__half2, hv.x);
        s = fmaf(__low2float(p), w0.x, s); s = fmaf(__high2float(p), w0.y, s);
        p = __builtin_bit_cast(__half2, hv.y);
        s = fmaf(__low2float(p), w0.z, s); s = fmaf(__high2float(p), w0.w, s);
        p = __builtin_bit_cast(__half2, hv.z);
        s = fmaf(__low2float(p), w1.x, s); s = fmaf(__high2float(p), w1.y, s);
        p = __builtin_bit_cast(__half2, hv.w);
        s = fmaf(__low2float(p), w1.z, s); s = fmaf(__high2float(p), w1.w, s);
#pragma unroll
        for (int off = 32; off; off >>= 1) s += __shfl_down(s, off, 64);
        if (lane == 0) out[b] = s + b_out[0];
    }
}

extern "C" void kernel_launch(void* const* d_in, const int* in_sizes, int n_in,
                              void* d_out, int out_size, void* d_ws, size_t ws_size,
                              hipStream_t stream) {
    const float* x     = (const float*)d_in[0];  // inputs [B,T,1]
    // d_in[1] = state (ignored; reference uses zero initial hidden state)
    const float* W_ih  = (const float*)d_in[2];
    const float* W_hh  = (const float*)d_in[3];
    const float* b_ih  = (const float*)d_in[4];
    const float* b_hh  = (const float*)d_in[5];
    const float* W_out = (const float*)d_in[6];
    const float* b_out = (const float*)d_in[7];

    rnn_cu<<<dim3(BB), dim3(512), 0, stream>>>(
        x, W_ih, W_hh, b_ih, b_hh, W_out, b_out, (float*)d_out);
}